// Round 2
// baseline (452.834 us; speedup 1.0000x reference)
//
#include <hip/hip_runtime.h>
#include <hip/hip_cooperative_groups.h>

namespace cg = cooperative_groups;

typedef unsigned short u16;
typedef unsigned int   u32;
typedef float f32x4  __attribute__((ext_vector_type(4)));
typedef short bf16x8 __attribute__((ext_vector_type(8)));
typedef short s16x4  __attribute__((ext_vector_type(4)));

__device__ __forceinline__ u16 f2b_rne(float x) {
    u32 u = __float_as_uint(x);
    return (u16)((u + 0x7fffu + ((u >> 16) & 1u)) >> 16);
}
__device__ __forceinline__ float b2f(u16 u) { return __uint_as_float((u32)u << 16); }
__device__ __forceinline__ void split1(float x, u16& h, u16& l) {
    h = f2b_rne(x);
    l = f2b_rne(x - b2f(h));
}
__device__ __forceinline__ void mk_frag(f32x4 a, f32x4 b, bf16x8& hi, bf16x8& lo) {
#pragma unroll
    for (int j = 0; j < 4; ++j) { u16 h, l; split1(a[j], h, l); hi[j] = (short)h; lo[j] = (short)l; }
#pragma unroll
    for (int j = 0; j < 4; ++j) { u16 h, l; split1(b[j], h, l); hi[4+j] = (short)h; lo[4+j] = (short)l; }
}

// ---------------------------------------------------------------------------
// gemm_tile: stage 16 rows of X (K=1000) into split hi/lo bf16 LDS planes
// (pitch 1008 u16 -> conflict-free b128 reads), then 16-wave GEMM vs We
// (wave = (ct = wv&3 col-tile, h = wv>>2 K-quarter)). Returns per-wave
// partial acc. Identical numerics to the proven kemb_all phase S+C.
// Barriers inside are block-uniform (whole block always calls).
// ---------------------------------------------------------------------------
__device__ __forceinline__ f32x4 gemm_tile(
    const float* __restrict__ X, int i0, int Mrows,
    const float* __restrict__ We,
    u16* XH, u16* XL, int wv, int lane, int l15, int q)
{
    {   // stage: wave wv stages row wv
        const int arow = min(i0 + wv, Mrows - 1);
        const float* xr = X + (size_t)arow * 1000;
#pragma unroll
        for (int j = 0; j < 4; ++j) {
            const int k4 = lane + j * 64;       // f32x4 index 0..249
            if (k4 < 250) {
                f32x4 v = *(const f32x4*)(xr + k4 * 4);
                s16x4 h4, l4;
#pragma unroll
                for (int jj = 0; jj < 4; ++jj) {
                    u16 hh, ll; split1(v[jj], hh, ll);
                    h4[jj] = (short)hh; l4[jj] = (short)ll;
                }
                *(s16x4*)(XH + wv * 1008 + k4 * 4) = h4;
                *(s16x4*)(XL + wv * 1008 + k4 * 4) = l4;
            }
        }
    }
    __syncthreads();

    const int ct = wv & 3, h = wv >> 2;
    f32x4 acc = {0.f, 0.f, 0.f, 0.f};
    const u16* ahp = XH + l15 * 1008;
    const u16* alp = XL + l15 * 1008;
    const float* wr = We + (size_t)(ct * 16 + l15) * 1000;

    const int kc0 = h * 256;
    const int kc1 = (h == 3) ? 992 : kc0 + 256;
    for (int kc = kc0; kc < kc1; kc += 32) {
        bf16x8 ah = *(const bf16x8*)(ahp + kc + q * 8);
        bf16x8 al = *(const bf16x8*)(alp + kc + q * 8);
        bf16x8 bh, bl;
        mk_frag(*(const f32x4*)(wr + kc + q * 8), *(const f32x4*)(wr + kc + q * 8 + 4), bh, bl);
        acc = __builtin_amdgcn_mfma_f32_16x16x32_bf16(ah, bh, acc, 0, 0, 0);
        acc = __builtin_amdgcn_mfma_f32_16x16x32_bf16(ah, bl, acc, 0, 0, 0);
        acc = __builtin_amdgcn_mfma_f32_16x16x32_bf16(al, bh, acc, 0, 0, 0);
    }
    if (h == 3) {                       // K tail 992..999 (q==0 live)
        bf16x8 ah = {0,0,0,0,0,0,0,0}, al = {0,0,0,0,0,0,0,0};
        bf16x8 bh = {0,0,0,0,0,0,0,0}, bl = {0,0,0,0,0,0,0,0};
        if (q == 0) {
            ah = *(const bf16x8*)(ahp + 992);
            al = *(const bf16x8*)(alp + 992);
            mk_frag(*(const f32x4*)(wr + 992), *(const f32x4*)(wr + 996), bh, bl);
        }
        acc = __builtin_amdgcn_mfma_f32_16x16x32_bf16(ah, bh, acc, 0, 0, 0);
        acc = __builtin_amdgcn_mfma_f32_16x16x32_bf16(ah, bl, acc, 0, 0, 0);
        acc = __builtin_amdgcn_mfma_f32_16x16x32_bf16(al, bh, acc, 0, 0, 0);
    }
    __syncthreads();                    // all plane reads done -> caller may overlay
    return acc;
}

// ---------------------------------------------------------------------------
// kmega<COOP>: the whole problem in one kernel (COOP=true, cooperative) or
// the cand+attention+MLP part (COOP=false, preceded by kprep).
//
// Per block (512 blocks x 1024 thr): cand tile GEMM -> ec tile kept in LDS
// (ECT, fp32 — ec NEVER touches global now). COOP: blocks {0,8,..,496} also
// compute rated tile r=blk>>3 -> er_th/ar; block 504 converts Wm1b; then
// __threadfence + grid.sync (device-scope, handles cross-XCD L2). Then the
// proven k3v10 phase sequence, with ecC global reads replaced by ECT, and
// softmax um loads hoisted ahead of the max-reduce.
// LDS: PL 64,512 B (planes; overlays: partials f32[0..4096), smt f32 @f4096,
// scores u16[16*1032], PA/PA2 f32[0..4096), H1 @f4096, H2 @f5120)
//  + ECT 4,096 + ACL 1,024 + SUMS 64 + XB16 4,352 = 74,048 B -> 2 blocks/CU.
// __launch_bounds__(1024,8) -> <=64 VGPR -> exactly 32 waves/CU co-resident
// (512-block cooperative grid fits exactly: 256 CU x 2 blocks).
// ---------------------------------------------------------------------------
template<bool COOP>
__global__ __launch_bounds__(1024, 8) void kmega(
    const float* __restrict__ cand, const float* __restrict__ rated,
    const float* __restrict__ We, const float* __restrict__ be,
    const float* __restrict__ Wa1, const float* __restrict__ ba1,
    const float* __restrict__ Wa2, const float* __restrict__ Wm1,
    const float* __restrict__ um, const float* __restrict__ bm1,
    const float* __restrict__ Wm2, const float* __restrict__ bm2,
    const float* __restrict__ Wm3, const float* __restrict__ bm3,
    u16* __restrict__ er_th, float* __restrict__ ar, u16* __restrict__ Wm1b,
    float* __restrict__ out)
{
    __shared__ __attribute__((aligned(16))) u16 PL[2 * 16 * 1008];
    __shared__ float ECT[16 * 64];
    __shared__ float ACL[256];
    __shared__ float SUMS[16];
    __shared__ __attribute__((aligned(16))) u16 XB16[16 * 136];
    float* Sf = (float*)PL;
    u16*  XH  = PL;
    u16*  XL  = PL + 16 * 1008;
    u16*  S16 = PL;                     // scores overlay (33,024 B)

    const int t    = threadIdx.x;
    const int wv   = t >> 6;
    const int lane = t & 63;
    const int l15  = lane & 15;
    const int q    = lane >> 4;
    const int blk  = blockIdx.x;
    const int b0   = blk * 16;

    // ---- cand tile GEMM -> partials -> ECT (fp32 ec tile, stays in LDS)
    {
        f32x4 acc = gemm_tile(cand, b0, 8192, We, XH, XL, wv, lane, l15, q);
        const int ct = wv & 3, h = wv >> 2;
#pragma unroll
        for (int r = 0; r < 4; ++r)
            Sf[h * 1024 + (q * 4 + r) * 64 + ct * 16 + l15] = acc[r];
        __syncthreads();
        const int b = t >> 6, e = t & 63;
        ECT[b * 64 + e] = be[e] + Sf[b * 64 + e] + Sf[1024 + b * 64 + e]
                                + Sf[2048 + b * 64 + e] + Sf[3072 + b * 64 + e];
        __syncthreads();                // partials read done -> planes reusable
    }

    if constexpr (COOP) {
        if ((blk & 7) == 0 && blk < 504) {          // rated tile r = blk>>3
            const int i0r = (blk >> 3) * 16;
            f32x4 a2 = gemm_tile(rated, i0r, 1000, We, XH, XL, wv, lane, l15, q);
            const int ct = wv & 3, h = wv >> 2;
#pragma unroll
            for (int r = 0; r < 4; ++r)
                Sf[h * 1024 + (q * 4 + r) * 64 + ct * 16 + l15] = a2[r];
            __syncthreads();
            {
                const int b = t >> 6, e = t & 63;
                float v = be[e] + Sf[b * 64 + e] + Sf[1024 + b * 64 + e]
                                + Sf[2048 + b * 64 + e] + Sf[3072 + b * 64 + e];
                if (i0r + b < 1000) er_th[(size_t)e * 1000 + (i0r + b)] = f2b_rne(v);
                Sf[4096 + b * 68 + e] = v;          // smt tile @ byte 16,384
            }
            __syncthreads();
            if (wv == 0) {              // ar = er @ W1r^T (split fp32-class)
                f32x4 a3 = {0.f, 0.f, 0.f, 0.f};
#pragma unroll
                for (int kc = 0; kc < 64; kc += 32) {
                    const float* ap = Sf + 4096 + l15 * 68 + kc + q * 8;
                    const float* bp = Wa1 + l15 * 128 + 64 + kc + q * 8;
                    bf16x8 ah, al, bh, bl;
                    mk_frag(*(const f32x4*)ap, *(const f32x4*)(ap + 4), ah, al);
                    mk_frag(*(const f32x4*)bp, *(const f32x4*)(bp + 4), bh, bl);
                    a3 = __builtin_amdgcn_mfma_f32_16x16x32_bf16(ah, bh, a3, 0, 0, 0);
                    a3 = __builtin_amdgcn_mfma_f32_16x16x32_bf16(ah, bl, a3, 0, 0, 0);
                    a3 = __builtin_amdgcn_mfma_f32_16x16x32_bf16(al, bh, a3, 0, 0, 0);
                }
#pragma unroll
                for (int r = 0; r < 4; ++r) {
                    int i = i0r + q * 4 + r;
                    if (i < 1000) ar[(size_t)i * 16 + l15] = a3[r];
                }
            }
        } else if (blk == 504) {        // Wm1 (64x128) -> bf16
            for (int idx = t; idx < 8192; idx += 1024)
                Wm1b[idx] = f2b_rne(Wm1[idx]);
        }
        __threadfence();
        cg::this_grid().sync();         // er_th / ar / Wm1b now grid-visible
    }

    // ======================= k3 phases (proven k3v10) =======================

    // P0: ACL[b][a] = ba1[a] + ec_tile[b] . W1c[a]   (ec from LDS now)
    if (t < 256) {
        const int a = t & 15, b = t >> 4;
        float acc = ba1[a];
        const float* w = Wa1 + a * 128;
#pragma unroll 8
        for (int e = 0; e < 64; ++e) acc += ECT[b * 64 + e] * w[e];
        ACL[b * 16 + a] = acc;
    }
    __syncthreads();                                        // B1

    // P1: thread = item i; scores for all 16 b -> u16 bf16 in S16.
    {
        const int i = t;
        if (i < 1000) {
            const f32x4* a4 = (const f32x4*)(ar + (size_t)i * 16);
            f32x4 r0 = a4[0], r1 = a4[1], r2 = a4[2], r3 = a4[3];
            float w2[16];
#pragma unroll
            for (int a = 0; a < 16; ++a) w2[a] = Wa2[a];
#pragma unroll 4
            for (int b = 0; b < 16; ++b) {
                const f32x4* ac4 = (const f32x4*)(ACL + b * 16);
                f32x4 c0 = ac4[0], c1 = ac4[1], c2 = ac4[2], c3 = ac4[3];
                float s0 = 0.f, s1 = 0.f;
                s0 += fmaxf(c0[0] + r0[0], 0.f) * w2[0];
                s1 += fmaxf(c0[1] + r0[1], 0.f) * w2[1];
                s0 += fmaxf(c0[2] + r0[2], 0.f) * w2[2];
                s1 += fmaxf(c0[3] + r0[3], 0.f) * w2[3];
                s0 += fmaxf(c1[0] + r1[0], 0.f) * w2[4];
                s1 += fmaxf(c1[1] + r1[1], 0.f) * w2[5];
                s0 += fmaxf(c1[2] + r1[2], 0.f) * w2[6];
                s1 += fmaxf(c1[3] + r1[3], 0.f) * w2[7];
                s0 += fmaxf(c2[0] + r2[0], 0.f) * w2[8];
                s1 += fmaxf(c2[1] + r2[1], 0.f) * w2[9];
                s0 += fmaxf(c2[2] + r2[2], 0.f) * w2[10];
                s1 += fmaxf(c2[3] + r2[3], 0.f) * w2[11];
                s0 += fmaxf(c3[0] + r3[0], 0.f) * w2[12];
                s1 += fmaxf(c3[1] + r3[1], 0.f) * w2[13];
                s0 += fmaxf(c3[2] + r3[2], 0.f) * w2[14];
                s1 += fmaxf(c3[3] + r3[3], 0.f) * w2[15];
                S16[b * 1032 + i] = f2b_rne(s0 + s1);
            }
        }
    }
    __syncthreads();                                        // B2

    // softmax: wave b. um loads issued FIRST (hide HBM burst behind reduce).
    {
        const int b = t >> 6, g = t & 63;
        float sv[16], uv[16];
        const float* umr = um + (size_t)(b0 + b) * 1000;
#pragma unroll
        for (int k = 0; k < 16; ++k) {
            int i = g + 64 * k;
            uv[k] = (i < 1000) ? umr[i] : 0.f;
        }
#pragma unroll
        for (int k = 0; k < 16; ++k) {
            int i = g + 64 * k;
            sv[k] = (i < 1000) ? b2f(S16[b * 1032 + i]) : -1e30f;
        }
        float m = -1e30f;
#pragma unroll
        for (int k = 0; k < 16; ++k) m = fmaxf(m, sv[k]);
#pragma unroll
        for (int k = 1; k < 64; k <<= 1) m = fmaxf(m, __shfl_xor(m, k));
        float sum = 0.f;
#pragma unroll
        for (int k = 0; k < 16; ++k) {
            int i = g + 64 * k;
            if (i < 1000) {
                float w = __expf(sv[k] - m);
                sum += w;
                S16[b * 1032 + i] = f2b_rne(w * uv[k]);     // P plane in place
            }
        }
#pragma unroll
        for (int k = 1; k < 64; k <<= 1) sum += __shfl_xor(sum, k);
        if (g == 0) SUMS[b] = 1.0f / sum;
    }
    __syncthreads();                                        // B3

    // P2: user_emb = P @ er^T via single-bf16 MFMA.
    {
        const int et = wv & 3, h = wv >> 2;
        const u16* php = S16 + l15 * 1032;
        const u16* bhp = er_th + (size_t)(et * 16 + l15) * 1000;
        f32x4 acc = {0.f, 0.f, 0.f, 0.f};

        const int kc0 = h * 256;
        const int kc1 = (h == 3) ? 992 : kc0 + 256;
        for (int kc = kc0; kc < kc1; kc += 32) {
            bf16x8 ah = *(const bf16x8*)(php + kc + q * 8);
            bf16x8 bh = *(const bf16x8*)(bhp + kc + q * 8);
            acc = __builtin_amdgcn_mfma_f32_16x16x32_bf16(ah, bh, acc, 0, 0, 0);
        }
        if (h == 3) {                   // K tail 992..999 (q==0 live)
            bf16x8 ah = {0,0,0,0,0,0,0,0}, bh = {0,0,0,0,0,0,0,0};
            if (q == 0) {
                ah = *(const bf16x8*)(php + 992);
                bh = *(const bf16x8*)(bhp + 992);
            }
            acc = __builtin_amdgcn_mfma_f32_16x16x32_bf16(ah, bh, acc, 0, 0, 0);
        }
        __syncthreads();                                    // B4: all P reads done
#pragma unroll
        for (int r = 0; r < 4; ++r)
            Sf[h * 1024 + (q * 4 + r) * 64 + et * 16 + l15] = acc[r];
    }
    __syncthreads();                                        // B5

    // P2b: combine K-quarters, scale, build x = [ec | user_emb] as bf16
    {
        const int b = t >> 6, e = t & 63;
        float v = (Sf[b * 64 + e] + Sf[1024 + b * 64 + e]
                 + Sf[2048 + b * 64 + e] + Sf[3072 + b * 64 + e]) * SUMS[b];
        XB16[b * 136 + 64 + e] = f2b_rne(v);
        XB16[b * 136 + e] = f2b_rne(ECT[b * 64 + e]);       // ec from LDS
    }
    __syncthreads();                                        // B6

    // MLP layer 1 via MFMA: h1 = relu(x @ Wm1^T + bm1).
    {
        const int nt = wv & 3, kh = wv >> 2;
        bf16x8 ah = *(const bf16x8*)(XB16 + l15 * 136 + kh * 32 + q * 8);
        bf16x8 bh = *(const bf16x8*)(Wm1b + (size_t)(nt * 16 + l15) * 128 + kh * 32 + q * 8);
        f32x4 acc = {0.f, 0.f, 0.f, 0.f};
        acc = __builtin_amdgcn_mfma_f32_16x16x32_bf16(ah, bh, acc, 0, 0, 0);
#pragma unroll
        for (int r = 0; r < 4; ++r)
            Sf[kh * 1024 + (q * 4 + r) * 64 + nt * 16 + l15] = acc[r];
    }
    __syncthreads();                                        // B7

    // reduce + bias + relu -> H1 (f32 @ f-idx 4096)
    {
        const int b = t >> 6, o = t & 63;
        float a = bm1[o] + Sf[b * 64 + o] + Sf[1024 + b * 64 + o]
                + Sf[2048 + b * 64 + o] + Sf[3072 + b * 64 + o];
        Sf[4096 + b * 64 + o] = fmaxf(a, 0.f);
    }
    __syncthreads();                                        // B8

    // MLP layer 2 (64->32): wave b, lane j<32
    {
        const int b = t >> 6, j = t & 63;
        if (j < 32) {
            float a = bm2[j];
            const float* wr = Wm2 + j * 64;
            const float* x = Sf + 4096 + b * 64;
#pragma unroll 8
            for (int k = 0; k < 64; ++k) a += x[k] * wr[k];
            Sf[5120 + b * 32 + j] = fmaxf(a, 0.f);
        }
    }
    __syncthreads();                                        // B9

    // MLP layer 3 (32->1): wave b reduce
    {
        const int b = t >> 6, j = t & 63;
        float p = (j < 32) ? Sf[5120 + b * 32 + j] * Wm3[j] : 0.f;
#pragma unroll
        for (int kk = 1; kk < 64; kk <<= 1) p += __shfl_xor(p, kk);
        if (j == 0) out[b0 + b] = p + bm3[0];
    }
}

// ---------------------------------------------------------------------------
// kprep: fallback-path producer (only used if cooperative launch is refused).
// Blocks 0..62: rated tile -> er_th, ar. Block 63: Wm1b convert.
// ---------------------------------------------------------------------------
__global__ __launch_bounds__(1024, 8) void kprep(
    const float* __restrict__ rated, const float* __restrict__ We,
    const float* __restrict__ be, const float* __restrict__ Wa1,
    const float* __restrict__ Wm1,
    u16* __restrict__ er_th, float* __restrict__ ar, u16* __restrict__ Wm1b)
{
    if (blockIdx.x == 63) {
        for (int idx = threadIdx.x; idx < 8192; idx += 1024)
            Wm1b[idx] = f2b_rne(Wm1[idx]);
        return;
    }
    __shared__ __attribute__((aligned(16))) u16 PL[2 * 16 * 1008];
    float* Sf = (float*)PL;
    u16* XH = PL;
    u16* XL = PL + 16 * 1008;

    const int t    = threadIdx.x;
    const int wv   = t >> 6;
    const int lane = t & 63;
    const int l15  = lane & 15;
    const int q    = lane >> 4;
    const int i0r  = blockIdx.x * 16;

    f32x4 a2 = gemm_tile(rated, i0r, 1000, We, XH, XL, wv, lane, l15, q);
    const int ct = wv & 3, h = wv >> 2;
#pragma unroll
    for (int r = 0; r < 4; ++r)
        Sf[h * 1024 + (q * 4 + r) * 64 + ct * 16 + l15] = a2[r];
    __syncthreads();
    {
        const int b = t >> 6, e = t & 63;
        float v = be[e] + Sf[b * 64 + e] + Sf[1024 + b * 64 + e]
                        + Sf[2048 + b * 64 + e] + Sf[3072 + b * 64 + e];
        if (i0r + b < 1000) er_th[(size_t)e * 1000 + (i0r + b)] = f2b_rne(v);
        Sf[4096 + b * 68 + e] = v;
    }
    __syncthreads();
    if (wv == 0) {
        f32x4 a3 = {0.f, 0.f, 0.f, 0.f};
#pragma unroll
        for (int kc = 0; kc < 64; kc += 32) {
            const float* ap = Sf + 4096 + l15 * 68 + kc + q * 8;
            const float* bp = Wa1 + l15 * 128 + 64 + kc + q * 8;
            bf16x8 ah, al, bh, bl;
            mk_frag(*(const f32x4*)ap, *(const f32x4*)(ap + 4), ah, al);
            mk_frag(*(const f32x4*)bp, *(const f32x4*)(bp + 4), bh, bl);
            a3 = __builtin_amdgcn_mfma_f32_16x16x32_bf16(ah, bh, a3, 0, 0, 0);
            a3 = __builtin_amdgcn_mfma_f32_16x16x32_bf16(ah, bl, a3, 0, 0, 0);
            a3 = __builtin_amdgcn_mfma_f32_16x16x32_bf16(al, bh, a3, 0, 0, 0);
        }
#pragma unroll
        for (int r = 0; r < 4; ++r) {
            int i = i0r + q * 4 + r;
            if (i < 1000) ar[(size_t)i * 16 + l15] = a3[r];
        }
    }
}

extern "C" void kernel_launch(void* const* d_in, const int* in_sizes, int n_in,
                              void* d_out, int out_size, void* d_ws, size_t ws_size,
                              hipStream_t stream) {
    const float* cand  = (const float*)d_in[0];   // (8192,1000) fp32
    const float* rated = (const float*)d_in[1];   // (1000,1000)
    const float* um    = (const float*)d_in[2];   // (8192,1000)
    const float* We    = (const float*)d_in[3];   // (64,1000)
    const float* be    = (const float*)d_in[4];   // (64,)
    const float* Wa1   = (const float*)d_in[5];   // (16,128)
    const float* ba1   = (const float*)d_in[6];   // (16,)
    const float* Wa2   = (const float*)d_in[7];   // (1,16)
    // d_in[8] = ba2: softmax-invariant (exact), skipped
    const float* Wm1   = (const float*)d_in[9];   // (64,128)
    const float* bm1   = (const float*)d_in[10];  // (64,)
    const float* Wm2   = (const float*)d_in[11];  // (32,64)
    const float* bm2   = (const float*)d_in[12];  // (32,)
    const float* Wm3   = (const float*)d_in[13];  // (1,32)
    const float* bm3   = (const float*)d_in[14];  // (1,)

    // ws (ec eliminated — lives in LDS now):
    //   ar 64,000 B + er_th 128,000 B + Wm1b 16,384 B = 208,384 B
    float* arw   = (float*)d_ws;                  // 16000 f
    u16*   er_th = (u16*)(arw + 16000);           // 64000 u16
    u16*   wm1b  = er_th + 64000;                 // 8192 u16
    float* out   = (float*)d_out;

    // Single cooperative launch (2 blocks/CU x 256 CU = 512 blocks, exact).
    void* kargs[] = {
        (void*)&cand, (void*)&rated, (void*)&We,  (void*)&be,
        (void*)&Wa1,  (void*)&ba1,   (void*)&Wa2, (void*)&Wm1,
        (void*)&um,   (void*)&bm1,   (void*)&Wm2, (void*)&bm2,
        (void*)&Wm3,  (void*)&bm3,
        (void*)&er_th, (void*)&arw, (void*)&wm1b, (void*)&out
    };
    auto kfn = kmega<true>;
    hipError_t err = hipLaunchCooperativeKernel(
        reinterpret_cast<const void*>(kfn), dim3(512), dim3(1024),
        kargs, 0, stream);
    if (err != hipSuccess) {
        (void)hipGetLastError();        // clear sticky error; use 2-launch path
        kprep<<<dim3(64), dim3(1024), 0, stream>>>(rated, We, be, Wa1, Wm1,
                                                   er_th, arw, wm1b);
        kmega<false><<<dim3(512), dim3(1024), 0, stream>>>(
            cand, rated, We, be, Wa1, ba1, Wa2, Wm1, um, bm1,
            Wm2, bm2, Wm3, bm3, er_th, arw, wm1b, out);
    }
}

// Round 3
// 158.135 us; speedup vs baseline: 2.8636x; 2.8636x over previous
//
#include <hip/hip_runtime.h>

typedef unsigned short u16;
typedef unsigned int   u32;
typedef float f32x4  __attribute__((ext_vector_type(4)));
typedef short bf16x8 __attribute__((ext_vector_type(8)));
typedef short s16x4  __attribute__((ext_vector_type(4)));

__device__ __forceinline__ u16 f2b_rne(float x) {
    u32 u = __float_as_uint(x);
    return (u16)((u + 0x7fffu + ((u >> 16) & 1u)) >> 16);
}
__device__ __forceinline__ float b2f(u16 u) { return __uint_as_float((u32)u << 16); }
__device__ __forceinline__ void split1(float x, u16& h, u16& l) {
    h = f2b_rne(x);
    l = f2b_rne(x - b2f(h));
}
__device__ __forceinline__ void mk_frag(f32x4 a, f32x4 b, bf16x8& hi, bf16x8& lo) {
#pragma unroll
    for (int j = 0; j < 4; ++j) { u16 h, l; split1(a[j], h, l); hi[j] = (short)h; lo[j] = (short)l; }
#pragma unroll
    for (int j = 0; j < 4; ++j) { u16 h, l; split1(b[j], h, l); hi[4+j] = (short)h; lo[4+j] = (short)l; }
}

// ---------------------------------------------------------------------------
// stage16: stage 16 rows of X (K=1000) into split hi/lo bf16 LDS planes
// (pitch 1008 u16 -> conflict-free b128 reads). Wave wv stages row wv.
// ---------------------------------------------------------------------------
__device__ __forceinline__ void stage16(
    const float* __restrict__ X, int i0, int Mrows,
    u16* XH, u16* XL, int wv, int lane)
{
    const int arow = min(i0 + wv, Mrows - 1);
    const float* xr = X + (size_t)arow * 1000;
#pragma unroll
    for (int j = 0; j < 4; ++j) {
        const int k4 = lane + j * 64;       // f32x4 index 0..249
        if (k4 < 250) {
            f32x4 v = *(const f32x4*)(xr + k4 * 4);
            s16x4 h4, l4;
#pragma unroll
            for (int jj = 0; jj < 4; ++jj) {
                u16 hh, ll; split1(v[jj], hh, ll);
                h4[jj] = (short)hh; l4[jj] = (short)ll;
            }
            *(s16x4*)(XH + wv * 1008 + k4 * 4) = h4;
            *(s16x4*)(XL + wv * 1008 + k4 * 4) = l4;
        }
    }
}

// ---------------------------------------------------------------------------
// gemm_tile_f32: full tile GEMM with in-register We conversion (fp32 path),
// used only by kprep's rated tiles (63 blocks — conversion cost irrelevant).
// Identical numerics to the proven rounds 5-9 path.
// ---------------------------------------------------------------------------
__device__ __forceinline__ f32x4 gemm_tile_f32(
    const float* __restrict__ X, int i0, int Mrows,
    const float* __restrict__ We,
    u16* XH, u16* XL, int wv, int lane, int l15, int q)
{
    stage16(X, i0, Mrows, XH, XL, wv, lane);
    __syncthreads();

    const int ct = wv & 3, h = wv >> 2;
    f32x4 acc = {0.f, 0.f, 0.f, 0.f};
    const u16* ahp = XH + l15 * 1008;
    const u16* alp = XL + l15 * 1008;
    const float* wr = We + (size_t)(ct * 16 + l15) * 1000;

    const int kc0 = h * 256;
    const int kc1 = (h == 3) ? 992 : kc0 + 256;
    for (int kc = kc0; kc < kc1; kc += 32) {
        bf16x8 ah = *(const bf16x8*)(ahp + kc + q * 8);
        bf16x8 al = *(const bf16x8*)(alp + kc + q * 8);
        bf16x8 bh, bl;
        mk_frag(*(const f32x4*)(wr + kc + q * 8), *(const f32x4*)(wr + kc + q * 8 + 4), bh, bl);
        acc = __builtin_amdgcn_mfma_f32_16x16x32_bf16(ah, bh, acc, 0, 0, 0);
        acc = __builtin_amdgcn_mfma_f32_16x16x32_bf16(ah, bl, acc, 0, 0, 0);
        acc = __builtin_amdgcn_mfma_f32_16x16x32_bf16(al, bh, acc, 0, 0, 0);
    }
    if (h == 3) {                       // K tail 992..999 (q==0 live)
        bf16x8 ah = {0,0,0,0,0,0,0,0}, al = {0,0,0,0,0,0,0,0};
        bf16x8 bh = {0,0,0,0,0,0,0,0}, bl = {0,0,0,0,0,0,0,0};
        if (q == 0) {
            ah = *(const bf16x8*)(ahp + 992);
            al = *(const bf16x8*)(alp + 992);
            mk_frag(*(const f32x4*)(wr + 992), *(const f32x4*)(wr + 996), bh, bl);
        }
        acc = __builtin_amdgcn_mfma_f32_16x16x32_bf16(ah, bh, acc, 0, 0, 0);
        acc = __builtin_amdgcn_mfma_f32_16x16x32_bf16(ah, bl, acc, 0, 0, 0);
        acc = __builtin_amdgcn_mfma_f32_16x16x32_bf16(al, bh, acc, 0, 0, 0);
    }
    __syncthreads();                    // all plane reads done -> caller overlays
    return acc;
}

// ---------------------------------------------------------------------------
// kprep (grid 68): blocks 0..62 rated tiles -> er_th (bf16 transposed) + ar;
// block 63: Wm1 -> Wm1b bf16; blocks 64..67: We -> Weh/Wel split-bf16 planes
// (64x1000 u16 each, pitch 1000 -> 16B-aligned rows, L2-resident for kmain).
// Stream order guarantees visibility to kmain (kernel boundary = cheap sync;
// in-kernel grid.sync measured at ~250us stall on this part — never again).
// ---------------------------------------------------------------------------
__global__ __launch_bounds__(1024, 8) void kprep(
    const float* __restrict__ rated, const float* __restrict__ We,
    const float* __restrict__ be, const float* __restrict__ Wa1,
    const float* __restrict__ Wm1,
    u16* __restrict__ er_th, float* __restrict__ ar, u16* __restrict__ Wm1b,
    u16* __restrict__ Weh, u16* __restrict__ Wel)
{
    const int blk = blockIdx.x;
    if (blk == 63) {                    // Wm1 (64x128) -> bf16
        for (int idx = threadIdx.x; idx < 8192; idx += 1024)
            Wm1b[idx] = f2b_rne(Wm1[idx]);
        return;
    }
    if (blk >= 64) {                    // We -> split hi/lo planes
        const int g = (blk - 64) * 1024 + threadIdx.x;   // [0, 4096)
        const int e0 = g * 16;
        if (e0 < 64000) {
#pragma unroll
            for (int j = 0; j < 4; ++j) {
                f32x4 v = *(const f32x4*)(We + e0 + j * 4);
                s16x4 h4, l4;
#pragma unroll
                for (int jj = 0; jj < 4; ++jj) {
                    u16 hh, ll; split1(v[jj], hh, ll);
                    h4[jj] = (short)hh; l4[jj] = (short)ll;
                }
                *(s16x4*)(Weh + e0 + j * 4) = h4;
                *(s16x4*)(Wel + e0 + j * 4) = l4;
            }
        }
        return;
    }

    __shared__ __attribute__((aligned(16))) u16 PL[2 * 16 * 1008];
    float* Sf = (float*)PL;
    u16* XH = PL;
    u16* XL = PL + 16 * 1008;

    const int t    = threadIdx.x;
    const int wv   = t >> 6;
    const int lane = t & 63;
    const int l15  = lane & 15;
    const int q    = lane >> 4;
    const int i0r  = blk * 16;

    f32x4 a2 = gemm_tile_f32(rated, i0r, 1000, We, XH, XL, wv, lane, l15, q);
    const int ct = wv & 3, h = wv >> 2;
#pragma unroll
    for (int r = 0; r < 4; ++r)
        Sf[h * 1024 + (q * 4 + r) * 64 + ct * 16 + l15] = a2[r];
    __syncthreads();
    {
        const int b = t >> 6, e = t & 63;
        float v = be[e] + Sf[b * 64 + e] + Sf[1024 + b * 64 + e]
                        + Sf[2048 + b * 64 + e] + Sf[3072 + b * 64 + e];
        if (i0r + b < 1000) er_th[(size_t)e * 1000 + (i0r + b)] = f2b_rne(v);
        Sf[4096 + b * 68 + e] = v;      // smt tile (pitch 68)
    }
    __syncthreads();
    if (wv == 0) {                      // ar = er @ W1r^T (split fp32-class)
        f32x4 a3 = {0.f, 0.f, 0.f, 0.f};
#pragma unroll
        for (int kc = 0; kc < 64; kc += 32) {
            const float* ap = Sf + 4096 + l15 * 68 + kc + q * 8;
            const float* bp = Wa1 + l15 * 128 + 64 + kc + q * 8;
            bf16x8 ah, al, bh, bl;
            mk_frag(*(const f32x4*)ap, *(const f32x4*)(ap + 4), ah, al);
            mk_frag(*(const f32x4*)bp, *(const f32x4*)(bp + 4), bh, bl);
            a3 = __builtin_amdgcn_mfma_f32_16x16x32_bf16(ah, bh, a3, 0, 0, 0);
            a3 = __builtin_amdgcn_mfma_f32_16x16x32_bf16(ah, bl, a3, 0, 0, 0);
            a3 = __builtin_amdgcn_mfma_f32_16x16x32_bf16(al, bh, a3, 0, 0, 0);
        }
#pragma unroll
        for (int r = 0; r < 4; ++r) {
            int i = i0r + q * 4 + r;
            if (i < 1000) ar[(size_t)i * 16 + l15] = a3[r];
        }
    }
}

// ---------------------------------------------------------------------------
// kmain (grid 512): cand tile GEMM (preconverted Weh/Wel planes — no f32->bf16
// conversion in the hot loop; body = 2 LDS b128 + 2 global b128 + 3 MFMA),
// ec tile kept in LDS (never touches global), then the proven k3v10 phases.
// LDS: PL 64,512 B (overlays: partials f32[0..4096), scores u16[16*1032],
// PA/PA2 f32, H1 @f4096, H2 @f5120) + ECT 4,096 + ACL 1,024 + SUMS 64
// + XB16 4,352 = 74,048 B -> 2 blocks/CU, 32 waves/CU.
// ---------------------------------------------------------------------------
__global__ __launch_bounds__(1024, 8) void kmain(
    const float* __restrict__ cand,
    const u16* __restrict__ Weh, const u16* __restrict__ Wel,
    const float* __restrict__ be,
    const float* __restrict__ Wa1, const float* __restrict__ ba1,
    const float* __restrict__ Wa2, const float* __restrict__ um,
    const float* __restrict__ bm1,
    const float* __restrict__ Wm2, const float* __restrict__ bm2,
    const float* __restrict__ Wm3, const float* __restrict__ bm3,
    const u16* __restrict__ er_th, const float* __restrict__ ar,
    const u16* __restrict__ Wm1b, float* __restrict__ out)
{
    __shared__ __attribute__((aligned(16))) u16 PL[2 * 16 * 1008];
    __shared__ float ECT[16 * 64];
    __shared__ float ACL[256];
    __shared__ float SUMS[16];
    __shared__ __attribute__((aligned(16))) u16 XB16[16 * 136];
    float* Sf = (float*)PL;
    u16*  XH  = PL;
    u16*  XL  = PL + 16 * 1008;
    u16*  S16 = PL;                     // scores overlay (33,024 B)

    const int t    = threadIdx.x;
    const int wv   = t >> 6;
    const int lane = t & 63;
    const int l15  = lane & 15;
    const int q    = lane >> 4;
    const int b0   = blockIdx.x * 16;

    // ---- cand tile GEMM (bf16-plane B operands) -> partials -> ECT
    {
        stage16(cand, b0, 8192, XH, XL, wv, lane);
        __syncthreads();

        const int ct = wv & 3, h = wv >> 2;
        f32x4 acc = {0.f, 0.f, 0.f, 0.f};
        const u16* ahp = XH + l15 * 1008;
        const u16* alp = XL + l15 * 1008;
        const u16* whp = Weh + (size_t)(ct * 16 + l15) * 1000;
        const u16* wlp = Wel + (size_t)(ct * 16 + l15) * 1000;

        const int kc0 = h * 256;
        const int kc1 = (h == 3) ? 992 : kc0 + 256;
#pragma unroll 2
        for (int kc = kc0; kc < kc1; kc += 32) {
            bf16x8 ah = *(const bf16x8*)(ahp + kc + q * 8);
            bf16x8 al = *(const bf16x8*)(alp + kc + q * 8);
            bf16x8 bh = *(const bf16x8*)(whp + kc + q * 8);
            bf16x8 bl = *(const bf16x8*)(wlp + kc + q * 8);
            acc = __builtin_amdgcn_mfma_f32_16x16x32_bf16(ah, bh, acc, 0, 0, 0);
            acc = __builtin_amdgcn_mfma_f32_16x16x32_bf16(ah, bl, acc, 0, 0, 0);
            acc = __builtin_amdgcn_mfma_f32_16x16x32_bf16(al, bh, acc, 0, 0, 0);
        }
        if (h == 3) {                   // K tail 992..999 (q==0 live)
            bf16x8 ah = {0,0,0,0,0,0,0,0}, al = {0,0,0,0,0,0,0,0};
            bf16x8 bh = {0,0,0,0,0,0,0,0}, bl = {0,0,0,0,0,0,0,0};
            if (q == 0) {
                ah = *(const bf16x8*)(ahp + 992);
                al = *(const bf16x8*)(alp + 992);
                bh = *(const bf16x8*)(whp + 992);
                bl = *(const bf16x8*)(wlp + 992);
            }
            acc = __builtin_amdgcn_mfma_f32_16x16x32_bf16(ah, bh, acc, 0, 0, 0);
            acc = __builtin_amdgcn_mfma_f32_16x16x32_bf16(ah, bl, acc, 0, 0, 0);
            acc = __builtin_amdgcn_mfma_f32_16x16x32_bf16(al, bh, acc, 0, 0, 0);
        }
        __syncthreads();                // all plane reads done -> overlay
#pragma unroll
        for (int r = 0; r < 4; ++r)
            Sf[h * 1024 + (q * 4 + r) * 64 + ct * 16 + l15] = acc[r];
        __syncthreads();
        const int b = t >> 6, e = t & 63;
        ECT[b * 64 + e] = be[e] + Sf[b * 64 + e] + Sf[1024 + b * 64 + e]
                                + Sf[2048 + b * 64 + e] + Sf[3072 + b * 64 + e];
        __syncthreads();                // partials read done -> planes reusable
    }

    // ======================= k3 phases (proven k3v10) =======================

    // P0: ACL[b][a] = ba1[a] + ec_tile[b] . W1c[a]   (ec from LDS)
    if (t < 256) {
        const int a = t & 15, b = t >> 4;
        float acc = ba1[a];
        const float* w = Wa1 + a * 128;
#pragma unroll 8
        for (int e = 0; e < 64; ++e) acc += ECT[b * 64 + e] * w[e];
        ACL[b * 16 + a] = acc;
    }
    __syncthreads();                                        // B1

    // P1: thread = item i; scores for all 16 b -> u16 bf16 in S16.
    {
        const int i = t;
        if (i < 1000) {
            const f32x4* a4 = (const f32x4*)(ar + (size_t)i * 16);
            f32x4 r0 = a4[0], r1 = a4[1], r2 = a4[2], r3 = a4[3];
            float w2[16];
#pragma unroll
            for (int a = 0; a < 16; ++a) w2[a] = Wa2[a];
#pragma unroll 4
            for (int b = 0; b < 16; ++b) {
                const f32x4* ac4 = (const f32x4*)(ACL + b * 16);
                f32x4 c0 = ac4[0], c1 = ac4[1], c2 = ac4[2], c3 = ac4[3];
                float s0 = 0.f, s1 = 0.f;
                s0 += fmaxf(c0[0] + r0[0], 0.f) * w2[0];
                s1 += fmaxf(c0[1] + r0[1], 0.f) * w2[1];
                s0 += fmaxf(c0[2] + r0[2], 0.f) * w2[2];
                s1 += fmaxf(c0[3] + r0[3], 0.f) * w2[3];
                s0 += fmaxf(c1[0] + r1[0], 0.f) * w2[4];
                s1 += fmaxf(c1[1] + r1[1], 0.f) * w2[5];
                s0 += fmaxf(c1[2] + r1[2], 0.f) * w2[6];
                s1 += fmaxf(c1[3] + r1[3], 0.f) * w2[7];
                s0 += fmaxf(c2[0] + r2[0], 0.f) * w2[8];
                s1 += fmaxf(c2[1] + r2[1], 0.f) * w2[9];
                s0 += fmaxf(c2[2] + r2[2], 0.f) * w2[10];
                s1 += fmaxf(c2[3] + r2[3], 0.f) * w2[11];
                s0 += fmaxf(c3[0] + r3[0], 0.f) * w2[12];
                s1 += fmaxf(c3[1] + r3[1], 0.f) * w2[13];
                s0 += fmaxf(c3[2] + r3[2], 0.f) * w2[14];
                s1 += fmaxf(c3[3] + r3[3], 0.f) * w2[15];
                S16[b * 1032 + i] = f2b_rne(s0 + s1);
            }
        }
    }
    __syncthreads();                                        // B2

    // softmax: wave b. um loads issued FIRST (hide HBM burst behind reduce).
    {
        const int b = t >> 6, g = t & 63;
        float sv[16], uv[16];
        const float* umr = um + (size_t)(b0 + b) * 1000;
#pragma unroll
        for (int k = 0; k < 16; ++k) {
            int i = g + 64 * k;
            uv[k] = (i < 1000) ? umr[i] : 0.f;
        }
#pragma unroll
        for (int k = 0; k < 16; ++k) {
            int i = g + 64 * k;
            sv[k] = (i < 1000) ? b2f(S16[b * 1032 + i]) : -1e30f;
        }
        float m = -1e30f;
#pragma unroll
        for (int k = 0; k < 16; ++k) m = fmaxf(m, sv[k]);
#pragma unroll
        for (int k = 1; k < 64; k <<= 1) m = fmaxf(m, __shfl_xor(m, k));
        float sum = 0.f;
#pragma unroll
        for (int k = 0; k < 16; ++k) {
            int i = g + 64 * k;
            if (i < 1000) {
                float w = __expf(sv[k] - m);
                sum += w;
                S16[b * 1032 + i] = f2b_rne(w * uv[k]);     // P plane in place
            }
        }
#pragma unroll
        for (int k = 1; k < 64; k <<= 1) sum += __shfl_xor(sum, k);
        if (g == 0) SUMS[b] = 1.0f / sum;
    }
    __syncthreads();                                        // B3

    // P2: user_emb = P @ er^T via single-bf16 MFMA.
    {
        const int et = wv & 3, h = wv >> 2;
        const u16* php = S16 + l15 * 1032;
        const u16* bhp = er_th + (size_t)(et * 16 + l15) * 1000;
        f32x4 acc = {0.f, 0.f, 0.f, 0.f};

        const int kc0 = h * 256;
        const int kc1 = (h == 3) ? 992 : kc0 + 256;
        for (int kc = kc0; kc < kc1; kc += 32) {
            bf16x8 ah = *(const bf16x8*)(php + kc + q * 8);
            bf16x8 bh = *(const bf16x8*)(bhp + kc + q * 8);
            acc = __builtin_amdgcn_mfma_f32_16x16x32_bf16(ah, bh, acc, 0, 0, 0);
        }
        if (h == 3) {                   // K tail 992..999 (q==0 live)
            bf16x8 ah = {0,0,0,0,0,0,0,0}, bh = {0,0,0,0,0,0,0,0};
            if (q == 0) {
                ah = *(const bf16x8*)(php + 992);
                bh = *(const bf16x8*)(bhp + 992);
            }
            acc = __builtin_amdgcn_mfma_f32_16x16x32_bf16(ah, bh, acc, 0, 0, 0);
        }
        __syncthreads();                                    // B4: all P reads done
#pragma unroll
        for (int r = 0; r < 4; ++r)
            Sf[h * 1024 + (q * 4 + r) * 64 + et * 16 + l15] = acc[r];
    }
    __syncthreads();                                        // B5

    // P2b: combine K-quarters, scale, build x = [ec | user_emb] as bf16
    {
        const int b = t >> 6, e = t & 63;
        float v = (Sf[b * 64 + e] + Sf[1024 + b * 64 + e]
                 + Sf[2048 + b * 64 + e] + Sf[3072 + b * 64 + e]) * SUMS[b];
        XB16[b * 136 + 64 + e] = f2b_rne(v);
        XB16[b * 136 + e] = f2b_rne(ECT[b * 64 + e]);       // ec from LDS
    }
    __syncthreads();                                        // B6

    // MLP layer 1 via MFMA: h1 = relu(x @ Wm1^T + bm1).
    {
        const int nt = wv & 3, kh = wv >> 2;
        bf16x8 ah = *(const bf16x8*)(XB16 + l15 * 136 + kh * 32 + q * 8);
        bf16x8 bh = *(const bf16x8*)(Wm1b + (size_t)(nt * 16 + l15) * 128 + kh * 32 + q * 8);
        f32x4 acc = {0.f, 0.f, 0.f, 0.f};
        acc = __builtin_amdgcn_mfma_f32_16x16x32_bf16(ah, bh, acc, 0, 0, 0);
#pragma unroll
        for (int r = 0; r < 4; ++r)
            Sf[kh * 1024 + (q * 4 + r) * 64 + nt * 16 + l15] = acc[r];
    }
    __syncthreads();                                        // B7

    // reduce + bias + relu -> H1 (f32 @ f-idx 4096)
    {
        const int b = t >> 6, o = t & 63;
        float a = bm1[o] + Sf[b * 64 + o] + Sf[1024 + b * 64 + o]
                + Sf[2048 + b * 64 + o] + Sf[3072 + b * 64 + o];
        Sf[4096 + b * 64 + o] = fmaxf(a, 0.f);
    }
    __syncthreads();                                        // B8

    // MLP layer 2 (64->32): wave b, lane j<32
    {
        const int b = t >> 6, j = t & 63;
        if (j < 32) {
            float a = bm2[j];
            const float* wr = Wm2 + j * 64;
            const float* x = Sf + 4096 + b * 64;
#pragma unroll 8
            for (int k = 0; k < 64; ++k) a += x[k] * wr[k];
            Sf[5120 + b * 32 + j] = fmaxf(a, 0.f);
        }
    }
    __syncthreads();                                        // B9

    // MLP layer 3 (32->1): wave b reduce
    {
        const int b = t >> 6, j = t & 63;
        float p = (j < 32) ? Sf[5120 + b * 32 + j] * Wm3[j] : 0.f;
#pragma unroll
        for (int kk = 1; kk < 64; kk <<= 1) p += __shfl_xor(p, kk);
        if (j == 0) out[b0 + b] = p + bm3[0];
    }
}

extern "C" void kernel_launch(void* const* d_in, const int* in_sizes, int n_in,
                              void* d_out, int out_size, void* d_ws, size_t ws_size,
                              hipStream_t stream) {
    const float* cand  = (const float*)d_in[0];   // (8192,1000) fp32
    const float* rated = (const float*)d_in[1];   // (1000,1000)
    const float* um    = (const float*)d_in[2];   // (8192,1000)
    const float* We    = (const float*)d_in[3];   // (64,1000)
    const float* be    = (const float*)d_in[4];   // (64,)
    const float* Wa1   = (const float*)d_in[5];   // (16,128)
    const float* ba1   = (const float*)d_in[6];   // (16,)
    const float* Wa2   = (const float*)d_in[7];   // (1,16)
    // d_in[8] = ba2: softmax-invariant (exact), skipped
    const float* Wm1   = (const float*)d_in[9];   // (64,128)
    const float* bm1   = (const float*)d_in[10];  // (64,)
    const float* Wm2   = (const float*)d_in[11];  // (32,64)
    const float* bm2   = (const float*)d_in[12];  // (32,)
    const float* Wm3   = (const float*)d_in[13];  // (1,32)
    const float* bm3   = (const float*)d_in[14];  // (1,)

    // ws layout (all 16B-aligned):
    //   ar    @      0:  64,000 B (16000 f32)
    //   er_th @ 64,000: 128,000 B (64000 u16)
    //   Wm1b  @192,000:  16,384 B ( 8192 u16)
    //   Weh   @208,384: 128,000 B (64000 u16)
    //   Wel   @336,384: 128,000 B (64000 u16)   total 464,384 B
    char* w = (char*)d_ws;
    float* arw   = (float*)(w);
    u16*   er_th = (u16*)(w + 64000);
    u16*   wm1b  = (u16*)(w + 192000);
    u16*   weh   = (u16*)(w + 208384);
    u16*   wel   = (u16*)(w + 336384);
    float* out   = (float*)d_out;

    kprep<<<dim3(68),  dim3(1024), 0, stream>>>(rated, We, be, Wa1, Wm1,
                                                er_th, arw, wm1b, weh, wel);
    kmain<<<dim3(512), dim3(1024), 0, stream>>>(cand, weh, wel, be, Wa1, ba1,
                                                Wa2, um, bm1, Wm2, bm2, Wm3,
                                                bm3, er_th, arw, wm1b, out);
}